// Round 2
// baseline (133.379 us; speedup 1.0000x reference)
//
#include <hip/hip_runtime.h>

#define D_DIM 256

__device__ __forceinline__ void flush_acc(float* __restrict__ out, int b,
                                          int lane, const float4& acc) {
    float* p = out + (size_t)b * D_DIM + lane * 4;
    unsafeAtomicAdd(p + 0, acc.x);
    unsafeAtomicAdd(p + 1, acc.y);
    unsafeAtomicAdd(p + 2, acc.z);
    unsafeAtomicAdd(p + 3, acc.w);
}

// One wave (64 lanes) processes a contiguous chunk of rows.
// Lane l owns columns [4l, 4l+4). Segment-sum accumulates in registers,
// flushed with fp32 HW atomics only on batch_id change / chunk end.
// batch_id is sorted, so flushes are rare (~B + #waves total).
__global__ __launch_bounds__(256) void attentive_readout_kernel(
    const float* __restrict__ x,
    const int* __restrict__ bid,     // harness converts integer inputs to int32
    const float* __restrict__ gw,
    const float* __restrict__ gb,
    float* __restrict__ out,
    int n, int rows_per_wave)
{
    int gtid = blockIdx.x * blockDim.x + threadIdx.x;
    int wave = gtid >> 6;
    int lane = threadIdx.x & 63;

    long long r0 = (long long)wave * rows_per_wave;
    if (r0 >= n) return;
    long long r1 = r0 + rows_per_wave;
    if (r1 > n) r1 = n;

    const float4 w4 = *(const float4*)(gw + lane * 4);
    const float bias = gb[0];

    float4 acc = make_float4(0.f, 0.f, 0.f, 0.f);
    int cur = bid[r0];

    for (long long r = r0; r < r1; ++r) {
        int b = bid[r];                // wave-uniform -> uniform branch
        if (b != cur) {
            flush_acc(out, cur, lane, acc);
            acc = make_float4(0.f, 0.f, 0.f, 0.f);
            cur = b;
        }
        float4 v = *(const float4*)(x + (size_t)r * D_DIM + lane * 4);
        float s = v.x * w4.x + v.y * w4.y + v.z * w4.z + v.w * w4.w;
        #pragma unroll
        for (int off = 32; off > 0; off >>= 1)
            s += __shfl_xor(s, off, 64);
        float g = 1.0f / (1.0f + __expf(-(s + bias)));
        acc.x += v.x * g;
        acc.y += v.y * g;
        acc.z += v.z * g;
        acc.w += v.w * g;
    }
    flush_acc(out, cur, lane, acc);
}

extern "C" void kernel_launch(void* const* d_in, const int* in_sizes, int n_in,
                              void* d_out, int out_size, void* d_ws, size_t ws_size,
                              hipStream_t stream) {
    const float* x   = (const float*)d_in[0];
    const int*   bid = (const int*)d_in[1];   // int32 per harness contract
    // d_in[2] = batch_size scalar (unused; B = out_size / D)
    const float* gw  = (const float*)d_in[3];
    const float* gb  = (const float*)d_in[4];
    float*       out = (float*)d_out;

    const int n = in_sizes[0] / D_DIM;   // 500000

    // d_out is poisoned (0xAA) before timing and never re-poisoned: zero it
    // every call (graph-capturable memset node).
    hipMemsetAsync(d_out, 0, (size_t)out_size * sizeof(float), stream);

    const int threads     = 256;               // 4 waves/block
    const int waves_total = 8192;              // ~61 rows per wave
    int rows_per_wave = (n + waves_total - 1) / waves_total;
    int waves_needed  = (n + rows_per_wave - 1) / rows_per_wave;
    int blocks        = (waves_needed + 3) / 4;

    attentive_readout_kernel<<<blocks, threads, 0, stream>>>(
        x, bid, gw, gb, out, n, rows_per_wave);
}